// Round 8
// baseline (196.543 us; speedup 1.0000x reference)
//
#include <hip/hip_runtime.h>
#include <hip/hip_fp16.h>
#include <hip/hip_bf16.h>

#define NT    2304   // tokens = 48*48
#define DIM   768
#define TD    2304   // 3*dim
#define NHEAD 12
#define HD    64
#define RANK  32
#define KA    832    // augmented K = 768 + 32 (uq) + 32 (uv)
#define NSPLIT 4
#define TILES  9     // 36 / NSPLIT

typedef __attribute__((ext_vector_type(8))) short short8;
typedef __attribute__((ext_vector_type(4))) short short4_t;
typedef __attribute__((ext_vector_type(4))) float floatx4;

__device__ __forceinline__ unsigned short f2bf(float f) {
    union { float f; unsigned u; } v; v.f = f;
    unsigned u = v.u + 0x7FFFu + ((v.u >> 16) & 1u);
    return (unsigned short)(u >> 16);
}
__device__ __forceinline__ float bf2f(unsigned short h) {
    union { unsigned u; float f; } v; v.u = ((unsigned)h) << 16; return v.f;
}
__device__ __forceinline__ float h2f(unsigned short u) {
    __half h = *(__half*)&u; return __half2float(h);
}
__device__ __forceinline__ unsigned pkbf(float a, float b) {   // v_cvt_pk_bf16_f32
    __hip_bfloat162 t = __float22bfloat162_rn(make_float2(a, b));
    unsigned r; __builtin_memcpy(&r, &t, 4); return r;
}
__device__ __forceinline__ void async16(const unsigned short* g, unsigned short* l) {
    __builtin_amdgcn_global_load_lds(
        (const __attribute__((address_space(1))) unsigned int*)g,
        (__attribute__((address_space(3))) unsigned int*)l, 16, 0, 0);
}

// ---------------------------------------------------------------------------
// 64x64 fp32->bf16 transpose tile helper
// ---------------------------------------------------------------------------
__device__ __forceinline__ void tr_tile(const float* __restrict__ src,
                                        unsigned short* __restrict__ dst,
                                        int N, int P, int n0, int k0,
                                        unsigned short* tile, int tid) {
    #pragma unroll
    for (int p = 0; p < 4; ++p) {
        int krow = (tid >> 4) + p * 16, n4 = (tid & 15) * 4;
        float4 v = *(const float4*)(src + (size_t)(k0 + krow) * N + n0 + n4);
        tile[krow * 71 + n4 + 0] = f2bf(v.x);
        tile[krow * 71 + n4 + 1] = f2bf(v.y);
        tile[krow * 71 + n4 + 2] = f2bf(v.z);
        tile[krow * 71 + n4 + 3] = f2bf(v.w);
    }
    __syncthreads();
    #pragma unroll
    for (int p = 0; p < 2; ++p) {
        int c = tid + p * 256;
        int nrow = c >> 3, k8 = (c & 7) * 8;
        short8 o;
        #pragma unroll
        for (int i = 0; i < 8; ++i) o[i] = (short)tile[(k8 + i) * 71 + nrow];
        *(short8*)(dst + (size_t)(n0 + nrow) * P + k0 + k8) = o;
    }
}

// ---------------------------------------------------------------------------
// Fused prep: [0,2304) FacT rows; [2304,2736) Wqkv^T; [2736,2880) Wp^T;
// [2880,2889) Fv fill.
// ---------------------------------------------------------------------------
__global__ __launch_bounds__(256)
void k_prep(const float* __restrict__ x, const float* __restrict__ Fu,
            const float* __restrict__ qF, const float* __restrict__ vF,
            const float* __restrict__ Wqkv, const float* __restrict__ Wp,
            const float* __restrict__ Fv,
            unsigned short* __restrict__ Ax, unsigned short* __restrict__ BqT,
            unsigned short* __restrict__ WpT) {
    __shared__ __align__(16) unsigned short tile[64 * 71];
    int b = blockIdx.x;
    int tid = threadIdx.x;
    if (b < NT) {
        float* part = (float*)tile;            // [8][32]
        float* us = part + 256;                // [32]
        int row = b;
        int r = tid & 31, p = tid >> 5;
        const float* xr = x + (size_t)row * DIM;
        if (tid < 96) {                        // vectorized bf16 cast of x row
            const float4* pp = (const float4*)(xr + tid * 8);
            float4 a = pp[0], bb = pp[1];
            short8 o;
            o[0] = (short)f2bf(a.x);  o[1] = (short)f2bf(a.y);
            o[2] = (short)f2bf(a.z);  o[3] = (short)f2bf(a.w);
            o[4] = (short)f2bf(bb.x); o[5] = (short)f2bf(bb.y);
            o[6] = (short)f2bf(bb.z); o[7] = (short)f2bf(bb.w);
            *(short8*)(Ax + (size_t)row * KA + tid * 8) = o;
        }
        float acc = 0.f;
        int k0 = p * (DIM / 8);
        for (int k = k0; k < k0 + DIM / 8; ++k)
            acc = fmaf(xr[k], Fu[k * RANK + r], acc);
        part[p * 32 + r] = acc;
        __syncthreads();
        if (tid < 32) {
            float s = 0.f;
            #pragma unroll
            for (int pp2 = 0; pp2 < 8; ++pp2) s += part[pp2 * 32 + tid];
            us[tid] = s;
        }
        __syncthreads();
        if (tid < 64) {
            int c = tid & 31;
            const float* F = (tid < 32) ? qF : vF;
            float s = 0.f;
            #pragma unroll
            for (int rr = 0; rr < RANK; ++rr) s = fmaf(us[rr], F[rr * RANK + c], s);
            int col = (tid < 32) ? (768 + c) : (800 + c);
            Ax[(size_t)row * KA + col] = f2bf(s);
        }
    } else if (b < NT + 432) {
        int i = b - NT;
        tr_tile(Wqkv, BqT, TD, KA, (i % 36) * 64, (i / 36) * 64, tile, tid);
    } else if (b < NT + 576) {
        int i = b - NT - 432;
        tr_tile(Wp, WpT, DIM, DIM, (i % 12) * 64, (i / 12) * 64, tile, tid);
    } else {
        int i = b - NT - 576;
        int n = i * 256 + tid;
        unsigned short* d = BqT + (size_t)n * KA;
        #pragma unroll 4
        for (int r = 0; r < 32; ++r) {
            d[768 + r] = (n < 768)   ? f2bf(Fv[r * 768 + n])          : (unsigned short)0;
            d[800 + r] = (n >= 1536) ? f2bf(Fv[r * 768 + (n - 1536)]) : (unsigned short)0;
        }
    }
}

// ---------------------------------------------------------------------------
// bf16 MFMA GEMM, BM=64, BN in {64,128}: C = A @ BT^T + bias. BK=64.
// global_load_lds(16B) staging, XOR-8 swizzle on the global source.
// FUSEV: cols >=1536 also written transposed into VtG[chan][token].
// (used with BN=128 for the qkv GEMM; r7 lesson: 128x128/324-block variant
//  loses to this on load balance — 648 blocks pack 2.5/CU vs 1.27/CU.)
// ---------------------------------------------------------------------------
template<int BN, int OUTF, int FUSEV>
__global__ __launch_bounds__(256)
void k_gemm64(const unsigned short* __restrict__ A,
              const unsigned short* __restrict__ BT,
              const float* __restrict__ bias, void* __restrict__ Cout,
              int N, int K, unsigned short* __restrict__ VtG) {
    __shared__ __align__(16) unsigned short As[64 * 64];
    __shared__ __align__(16) unsigned short Bs[BN * 64];
    constexpr int NJ = BN / 32;
    int tid = threadIdx.x;
    int m0 = blockIdx.y * 64, n0 = blockIdx.x * BN;
    int lane = tid & 63, wave = tid >> 6;
    int wr = wave >> 1, wc = wave & 1;
    int lm = lane & 15, quad = lane >> 4;

    int srow = tid >> 3;                         // 0..31
    int sgrp = ((tid & 7) ^ (srow & 7)) * 8;     // swizzled k-group (global src)
    const unsigned short* gA0 = A + (size_t)(m0 + srow) * K + sgrp;
    const unsigned short* gA1 = A + (size_t)(m0 + 32 + srow) * K + sgrp;
    const unsigned short* gB0 = BT + (size_t)(n0 + srow) * K + sgrp;
    const unsigned short* gB1 = BT + (size_t)(n0 + 32 + srow) * K + sgrp;
    unsigned short* lA0 = As + wave * 512;       // wave-uniform bases
    unsigned short* lA1 = As + 2048 + wave * 512;
    unsigned short* lB0 = Bs + wave * 512;
    unsigned short* lB1 = Bs + 2048 + wave * 512;

    floatx4 acc[2][NJ];
    #pragma unroll
    for (int i = 0; i < 2; ++i)
        #pragma unroll
        for (int j = 0; j < NJ; ++j) acc[i][j] = (floatx4){0.f, 0.f, 0.f, 0.f};

    for (int kt = 0; kt < K; kt += 64) {
        async16(gA0 + kt, lA0);
        async16(gA1 + kt, lA1);
        async16(gB0 + kt, lB0);
        async16(gB1 + kt, lB1);
        if constexpr (BN == 128) {
            const unsigned short* gB2 = BT + (size_t)(n0 + 64 + srow) * K + sgrp;
            const unsigned short* gB3 = BT + (size_t)(n0 + 96 + srow) * K + sgrp;
            async16(gB2 + kt, Bs + 4096 + wave * 512);
            async16(gB3 + kt, Bs + 6144 + wave * 512);
        }
        __syncthreads();
        #pragma unroll
        for (int kk = 0; kk < 2; ++kk) {
            short8 af[2];
            #pragma unroll
            for (int t2 = 0; t2 < 2; ++t2) {
                int row = wr * 32 + t2 * 16 + lm;
                int g = kk * 4 + quad;
                af[t2] = *(const short8*)(As + row * 64 + ((g ^ (row & 7)) * 8));
            }
            #pragma unroll
            for (int j = 0; j < NJ; ++j) {
                int row = wc * (BN / 2) + j * 16 + lm;
                int g = kk * 4 + quad;
                short8 bq = *(const short8*)(Bs + row * 64 + ((g ^ (row & 7)) * 8));
                acc[0][j] = __builtin_amdgcn_mfma_f32_16x16x32_bf16(af[0], bq, acc[0][j], 0, 0, 0);
                acc[1][j] = __builtin_amdgcn_mfma_f32_16x16x32_bf16(af[1], bq, acc[1][j], 0, 0, 0);
            }
        }
        __syncthreads();
    }

    #pragma unroll
    for (int jt = 0; jt < NJ; ++jt) {
        int col = n0 + wc * (BN / 2) + jt * 16 + lm;
        float bv = bias[col];
        #pragma unroll
        for (int it = 0; it < 2; ++it) {
            int rowb = m0 + wr * 32 + it * 16 + quad * 4;
            #pragma unroll
            for (int r = 0; r < 4; ++r) {
                float val = acc[it][jt][r] + bv;
                if (OUTF)
                    ((float*)Cout)[(size_t)(rowb + r) * N + col] = val;
                else
                    ((unsigned short*)Cout)[(size_t)(rowb + r) * N + col] = f2bf(val);
            }
            if (FUSEV && col >= 1536) {
                short4_t vt;
                #pragma unroll
                for (int r = 0; r < 4; ++r) vt[r] = (short)f2bf(acc[it][jt][r] + bv);
                *(short4_t*)(VtG + (size_t)(col - 1536) * NT + rowb) = vt;
            }
        }
    }
}

// ---------------------------------------------------------------------------
// Fused combine + proj GEMM: out = (sum_s Opart[s] / sum_s Lpart[s]) @ WpT^T
// + bias, fp32 out. BM=BN=64, K=DIM, one K-step per head (HD=64, so the
// 1/l normalizer is constant within a K-step).
// A-operand is reg-staged (8 short8 Opart loads + 8 Lpart scalars per step,
// prefetched for step h+1 under step h's MFMA), combined/normalized in
// registers, ds_written to the XOR-swizzled layout the MFMA loop reads.
// B-operand keeps global_load_lds. Replaces k_comb + old proj kernel:
// saves one launch and a 7 MB aob round-trip.
// ---------------------------------------------------------------------------
__global__ __launch_bounds__(256)
void k_proj(const unsigned short* __restrict__ Opart,
            const float* __restrict__ Lpart,
            const unsigned short* __restrict__ WpT,
            const float* __restrict__ bias, float* __restrict__ Cout) {
    __shared__ __align__(16) unsigned short As[64 * 64];
    __shared__ __align__(16) unsigned short Bs[64 * 64];
    int tid = threadIdx.x;
    int m0 = blockIdx.y * 64, n0 = blockIdx.x * 64;
    int lane = tid & 63, wave = tid >> 6;
    int wr = wave >> 1, wc = wave & 1;
    int lm = lane & 15, quad = lane >> 4;

    int srow = tid >> 3;                         // 0..31
    int scc = (tid & 7) * 8;                     // linear channel group
    int sgrp = ((tid & 7) ^ (srow & 7)) * 8;     // swizzled group
    int sw0 = srow * 64 + sgrp;                  // (row+32 has same row&7)
    int sw1 = sw0 + 32 * 64;
    int t0 = m0 + srow, t1 = t0 + 32;

    const unsigned short* gB0 = WpT + (size_t)(n0 + srow) * DIM + sgrp;
    const unsigned short* gB1 = WpT + (size_t)(n0 + 32 + srow) * DIM + sgrp;
    unsigned short* lB0 = Bs + wave * 512;       // wave-uniform bases
    unsigned short* lB1 = Bs + 2048 + wave * 512;

    // raw A fragments + row-sums for the current K-step (head)
    short8 a0[NSPLIT], a1[NSPLIT];
    float l0[NSPLIT], l1[NSPLIT];
    #pragma unroll
    for (int s = 0; s < NSPLIT; ++s) {
        a0[s] = *(const short8*)(Opart + (size_t)s * NT * DIM + (size_t)t0 * DIM + scc);
        a1[s] = *(const short8*)(Opart + (size_t)s * NT * DIM + (size_t)t1 * DIM + scc);
        l0[s] = Lpart[(size_t)s * NHEAD * NT + t0];
        l1[s] = Lpart[(size_t)s * NHEAD * NT + t1];
    }

    floatx4 acc[2][2];
    #pragma unroll
    for (int i = 0; i < 2; ++i)
        #pragma unroll
        for (int j = 0; j < 2; ++j) acc[i][j] = (floatx4){0.f, 0.f, 0.f, 0.f};

    for (int h = 0; h < NHEAD; ++h) {
        // combine + normalize current fragments, stage to LDS (swizzled)
        float inv0 = 1.f / (l0[0] + l0[1] + l0[2] + l0[3]);
        float inv1 = 1.f / (l1[0] + l1[1] + l1[2] + l1[3]);
        union { unsigned u[4]; short8 s8; } o0, o1;
        #pragma unroll
        for (int i = 0; i < 4; ++i) {
            float e0 = (bf2f((unsigned short)a0[0][2 * i])     + bf2f((unsigned short)a0[1][2 * i])
                      + bf2f((unsigned short)a0[2][2 * i])     + bf2f((unsigned short)a0[3][2 * i])) * inv0;
            float f0 = (bf2f((unsigned short)a0[0][2 * i + 1]) + bf2f((unsigned short)a0[1][2 * i + 1])
                      + bf2f((unsigned short)a0[2][2 * i + 1]) + bf2f((unsigned short)a0[3][2 * i + 1])) * inv0;
            o0.u[i] = pkbf(e0, f0);
            float e1 = (bf2f((unsigned short)a1[0][2 * i])     + bf2f((unsigned short)a1[1][2 * i])
                      + bf2f((unsigned short)a1[2][2 * i])     + bf2f((unsigned short)a1[3][2 * i])) * inv1;
            float f1 = (bf2f((unsigned short)a1[0][2 * i + 1]) + bf2f((unsigned short)a1[1][2 * i + 1])
                      + bf2f((unsigned short)a1[2][2 * i + 1]) + bf2f((unsigned short)a1[3][2 * i + 1])) * inv1;
            o1.u[i] = pkbf(e1, f1);
        }
        *(short8*)(As + sw0) = o0.s8;
        *(short8*)(As + sw1) = o1.s8;
        async16(gB0 + h * 64, lB0);
        async16(gB1 + h * 64, lB1);
        __syncthreads();                         // staging visible

        // prefetch next head's raw fragments (hides under MFMA)
        if (h + 1 < NHEAD) {
            int kt = (h + 1) * 64;
            #pragma unroll
            for (int s = 0; s < NSPLIT; ++s) {
                a0[s] = *(const short8*)(Opart + (size_t)s * NT * DIM + (size_t)t0 * DIM + kt + scc);
                a1[s] = *(const short8*)(Opart + (size_t)s * NT * DIM + (size_t)t1 * DIM + kt + scc);
                l0[s] = Lpart[((size_t)s * NHEAD + h + 1) * NT + t0];
                l1[s] = Lpart[((size_t)s * NHEAD + h + 1) * NT + t1];
            }
        }

        #pragma unroll
        for (int kk = 0; kk < 2; ++kk) {
            short8 af[2];
            #pragma unroll
            for (int t2 = 0; t2 < 2; ++t2) {
                int row = wr * 32 + t2 * 16 + lm;
                int g = kk * 4 + quad;
                af[t2] = *(const short8*)(As + row * 64 + ((g ^ (row & 7)) * 8));
            }
            #pragma unroll
            for (int j = 0; j < 2; ++j) {
                int row = wc * 32 + j * 16 + lm;
                int g = kk * 4 + quad;
                short8 bq = *(const short8*)(Bs + row * 64 + ((g ^ (row & 7)) * 8));
                acc[0][j] = __builtin_amdgcn_mfma_f32_16x16x32_bf16(af[0], bq, acc[0][j], 0, 0, 0);
                acc[1][j] = __builtin_amdgcn_mfma_f32_16x16x32_bf16(af[1], bq, acc[1][j], 0, 0, 0);
            }
        }
        __syncthreads();                         // As/Bs consumed: next stage safe
    }

    #pragma unroll
    for (int jt = 0; jt < 2; ++jt) {
        int col = n0 + wc * 32 + jt * 16 + lm;
        float bv = bias[col];
        #pragma unroll
        for (int it = 0; it < 2; ++it) {
            int rowb = m0 + wr * 32 + it * 16 + quad * 4;
            #pragma unroll
            for (int r = 0; r < 4; ++r)
                Cout[(size_t)(rowb + r) * DIM + col] = acc[it][jt][r] + bv;
        }
    }
}

// ---------------------------------------------------------------------------
// Rel-pos bias tables via MFMA. Stored as half, pre-multiplied by log2(e).
//   which=0: BhG[h][j][t]   (j = key h-coord)
//   which=1: BwT[h][t][j]   (j = key w-coord)  -- TRANSPOSED layout
// ---------------------------------------------------------------------------
__global__ __launch_bounds__(256)
void k_bias(const unsigned short* __restrict__ qkv, const float* __restrict__ rph,
            const float* __restrict__ rpw, unsigned short* __restrict__ BhG,
            unsigned short* __restrict__ BwT) {
    __shared__ __align__(16) unsigned short Qs[48 * 68];
    __shared__ __align__(16) unsigned short Ts[48 * 68];
    int tid = threadIdx.x;
    int pos = blockIdx.x, h = blockIdx.y, which = blockIdx.z;
    const float* tab = which ? rpw : rph;
    for (int idx = tid; idx < 48 * 8; idx += 256) {
        int row = idx >> 3, c8 = (idx & 7) * 8;
        int t = which ? (row * 48 + pos) : (pos * 48 + row);
        *(short8*)(Qs + row * 68 + c8) =
            *(const short8*)(qkv + (size_t)t * TD + h * HD + c8);
    }
    for (int idx = tid; idx < 48 * 8; idx += 256) {
        int j = idx >> 3, c8 = (idx & 7) * 8;
        const float* src = tab + (size_t)(pos + 47 - j) * HD + c8;
        short8 o;
        #pragma unroll
        for (int i = 0; i < 8; ++i) o[i] = (short)f2bf(src[i]);
        *(short8*)(Ts + j * 68 + c8) = o;
    }
    __syncthreads();
    int lane = tid & 63, wave = tid >> 6;
    int lm = lane & 15, quad = lane >> 4;
    for (int tt = wave; tt < 9; tt += 4) {
        int rt = tt / 3, jt = tt - rt * 3;
        floatx4 acc = (floatx4){0.f, 0.f, 0.f, 0.f};
        #pragma unroll
        for (int kt = 0; kt < 2; ++kt) {
            short8 a = *(const short8*)(Qs + (rt * 16 + lm) * 68 + kt * 32 + quad * 8);
            short8 bb = *(const short8*)(Ts + (jt * 16 + lm) * 68 + kt * 32 + quad * 8);
            acc = __builtin_amdgcn_mfma_f32_16x16x32_bf16(a, bb, acc, 0, 0, 0);
        }
        int j = jt * 16 + lm;
        int r0 = rt * 16 + quad * 4;
        if (which == 0) {
            short4_t o;
            #pragma unroll
            for (int r = 0; r < 4; ++r) {
                __half hh = __float2half(acc[r] * 1.44269504f);
                o[r] = *(short*)&hh;
            }
            *(short4_t*)(BhG + (size_t)(h * 48 + j) * NT + pos * 48 + r0) = o;
        } else {
            #pragma unroll
            for (int r = 0; r < 4; ++r) {
                __half hh = __float2half(acc[r] * 1.44269504f);
                int t = (r0 + r) * 48 + pos;
                BwT[((size_t)h * NT + t) * 48 + j] = *(unsigned short*)&hh;
            }
        }
    }
}

// ---------------------------------------------------------------------------
// MFMA flash attention, 4-way key split, S^T layout. ROUND-3 STRUCTURE
// (best measured): 2 barriers/tile, register K/V double-buffer, separate
// Ps buffer, swizzled stride-64 tiles, LDS 32640 B -> 5 blocks/CU.
// ---------------------------------------------------------------------------
__global__ __launch_bounds__(256, 5)
void k_attn(const unsigned short* __restrict__ qkv,
            const unsigned short* __restrict__ VtG,
            const unsigned short* __restrict__ BhG,
            const unsigned short* __restrict__ BwT,
            unsigned short* __restrict__ Opart, float* __restrict__ Lpart) {
    __shared__ __align__(16) unsigned short Ks[64 * 64];   // K tile (swizzled)
    __shared__ __align__(16) unsigned short Vts[64 * 64];  // V^T tile (swizzled)
    __shared__ __align__(16) unsigned short Ps[64 * 64];   // Q stage, then P (swizzled)
    __shared__ __align__(16) unsigned short BhS[12 * 64];  // [hj_local][qrow] half
    __shared__ __align__(16) unsigned short BwS[64 * 48];  // [qrow][wj] half

    int tid = threadIdx.x;
    int lane = tid & 63, wave = tid >> 6;
    int lm = lane & 15, quad = lane >> 4;
    int i0 = blockIdx.x * 64, h = blockIdx.y, z = blockIdx.z;
    int qrow = wave * 16 + lm;                   // this lane's q-row (local)
    int j0 = z * TILES * 64;

    int row0 = tid >> 3, cc0 = (tid & 7) * 8;
    int row1 = row0 + 32;
    int sw0 = row0 * 64 + (((tid & 7) ^ (row0 & 7)) << 3);
    int sw1 = row1 * 64 + (((tid & 7) ^ (row1 & 7)) << 3);

    // stage Q into Ps (swizzled), then read fragments
    *(short8*)(Ps + sw0) =
        *(const short8*)(qkv + (size_t)(i0 + row0) * TD + h * HD + cc0);
    *(short8*)(Ps + sw1) =
        *(const short8*)(qkv + (size_t)(i0 + row1) * TD + h * HD + cc0);
    __syncthreads();
    short8 qf[2];
    qf[0] = *(const short8*)(Ps + qrow * 64 + ((quad ^ (qrow & 7)) << 3));
    qf[1] = *(const short8*)(Ps + qrow * 64 + (((4 + quad) ^ (qrow & 7)) << 3));

    // stage bias tables: BhS only 12 local hj rows [hj][qrow]; BwS [qrow][wj]
    if (tid < 192) {
        int j = tid >> 4, r4 = (tid & 15) * 4;
        *(short4_t*)(BhS + j * 64 + r4) =
            *(const short4_t*)(BhG + (size_t)(h * 48 + z * 12 + j) * NT + i0 + r4);
    }
    for (int idx = tid; idx < 64 * 6; idx += 256) {
        int row = idx / 6, c8 = (idx - row * 6) * 8;
        *(short8*)(BwS + row * 48 + c8) =
            *(const short8*)(BwT + ((size_t)h * NT + i0 + row) * 48 + c8);
    }

    // register double-buffer of K/V rows
    const unsigned short* gK = qkv + (size_t)(j0 + row0) * TD + 768 + h * HD + cc0;
    const unsigned short* gV = VtG + (size_t)(h * HD + row0) * NT + j0 + cc0;
    short8 kr0 = *(const short8*)gK;
    short8 kr1 = *(const short8*)(gK + (size_t)32 * TD);
    short8 vr0 = *(const short8*)gV;
    short8 vr1 = *(const short8*)(gV + (size_t)32 * NT);

    floatx4 o_acc[4];
    float lp = 0.f;
    #pragma unroll
    for (int nt = 0; nt < 4; ++nt) o_acc[nt] = (floatx4){0.f, 0.f, 0.f, 0.f};

    for (int t = 0; t < TILES; ++t) {
        *(short8*)(Ks + sw0) = kr0;
        *(short8*)(Ks + sw1) = kr1;
        *(short8*)(Vts + sw0) = vr0;
        *(short8*)(Vts + sw1) = vr1;
        __syncthreads();                         // staging visible (+Q/bias on t=0)

        // S^T = K Q^T  (A = K-frag, B = Q-frag)
        floatx4 s_acc[4];
        #pragma unroll
        for (int nt = 0; nt < 4; ++nt) s_acc[nt] = (floatx4){0.f, 0.f, 0.f, 0.f};
        #pragma unroll
        for (int kt = 0; kt < 2; ++kt)
            #pragma unroll
            for (int nt = 0; nt < 4; ++nt) {
                int row = nt * 16 + lm;
                short8 kf = *(const short8*)(Ks + row * 64 + (((kt * 4 + quad) ^ (row & 7)) << 3));
                s_acc[nt] = __builtin_amdgcn_mfma_f32_16x16x32_bf16(
                    kf, qf[kt], s_acc[nt], 0, 0, 0);
            }

        // prefetch next tile K/V into registers (hides under epilogue/PV)
        if (t + 1 < TILES) {
            gK += 64 * TD; gV += 64;
            kr0 = *(const short8*)gK;
            kr1 = *(const short8*)(gK + (size_t)32 * TD);
            vr0 = *(const short8*)gV;
            vr1 = *(const short8*)(gV + (size_t)32 * NT);
        }

        // epilogue: lane owns keys nt*16+quad*4..+3 for its single q-row
        int base = t * 64 + quad * 4;            // split-local key index
        int hj0 = base / 48;
        int wjb = base - hj0 * 48;
        #pragma unroll
        for (int nt = 0; nt < 4; ++nt) {
            int wj = wjb + nt * 16;
            int hj = hj0 + (wj >= 48 ? 1 : 0);   // local hj in [0,12)
            wj -= (wj >= 48 ? 48 : 0);
            float bh = h2f(BhS[hj * 64 + qrow]);
            short4_t bw4 = *(const short4_t*)(BwS + qrow * 48 + wj);
            float pe[4];
            #pragma unroll
            for (int r = 0; r < 4; ++r) {
                float b = bh + h2f((unsigned short)bw4[r]);
                pe[r] = exp2f(fmaf(0.18033688f, s_acc[nt][r], b));
                lp += pe[r];
            }
            union { unsigned u[2]; short4_t s; } pk;
            pk.u[0] = pkbf(pe[0], pe[1]);
            pk.u[1] = pkbf(pe[2], pe[3]);
            int c = nt * 16 + quad * 4;
            *(short4_t*)(Ps + qrow * 64 + (((c >> 3) ^ (qrow & 7)) << 3)
                         + ((quad & 1) << 2)) = pk.s;
        }

        // O += P V : pf from wave-private Ps rows, vf from Vts
        #pragma unroll
        for (int kt = 0; kt < 2; ++kt) {
            short8 pf = *(const short8*)(Ps + qrow * 64 + (((kt * 4 + quad) ^ (qrow & 7)) << 3));
            #pragma unroll
            for (int nt = 0; nt < 4; ++nt) {
                int row = nt * 16 + lm;
                short8 vf = *(const short8*)(Vts + row * 64 + (((kt * 4 + quad) ^ (row & 7)) << 3));
                o_acc[nt] = __builtin_amdgcn_mfma_f32_16x16x32_bf16(
                    pf, vf, o_acc[nt], 0, 0, 0);
            }
        }
        __syncthreads();                         // K/V consumed: next stage safe
    }

    // row sums: lane holds partial for its q-row over its quad's keys
    lp += __shfl_xor(lp, 16);
    lp += __shfl_xor(lp, 32);
    if (quad == 0)
        Lpart[((size_t)z * NHEAD + h) * NT + i0 + qrow] = lp;

    unsigned short* op = Opart + (size_t)z * NT * DIM;
    #pragma unroll
    for (int nt = 0; nt < 4; ++nt)
        #pragma unroll
        for (int r = 0; r < 4; ++r)
            op[(size_t)(i0 + wave * 16 + quad * 4 + r) * DIM + h * HD + nt * 16 + lm]
                = f2bf(o_acc[nt][r]);
}

// ---------------------------------------------------------------------------
extern "C" void kernel_launch(void* const* d_in, const int* in_sizes, int n_in,
                              void* d_out, int out_size, void* d_ws, size_t ws_size,
                              hipStream_t stream) {
    const float* x    = (const float*)d_in[0];
    const float* Wqkv = (const float*)d_in[1];
    const float* bqkv = (const float*)d_in[2];
    const float* Fu   = (const float*)d_in[3];
    const float* Fv   = (const float*)d_in[4];
    const float* qF   = (const float*)d_in[5];
    const float* vF   = (const float*)d_in[6];
    const float* rph  = (const float*)d_in[7];
    const float* rpw  = (const float*)d_in[8];
    const float* Wp   = (const float*)d_in[9];
    const float* bp   = (const float*)d_in[10];

    unsigned short* ws   = (unsigned short*)d_ws;
    unsigned short* qkvb = ws;                               // [2304][2304]
    unsigned short* WpT  = qkvb + (size_t)NT * TD;           // [768][768]
    unsigned short* VtG  = WpT  + (size_t)DIM * DIM;         // [768][2304]
    unsigned short* BhG  = VtG  + (size_t)DIM * NT;          // [12][48][2304] half
    unsigned short* BwT  = BhG  + (size_t)NHEAD * 48 * NT;   // [12][2304][48] half
    float*          Lpart = (float*)(BwT + (size_t)NHEAD * NT * 48); // [4][12][2304]
    unsigned short* tail = (unsigned short*)(Lpart + (size_t)NSPLIT * NHEAD * NT);
    unsigned short* Ax   = tail;                             // [2304][832] (early)
    unsigned short* BqT  = Ax + (size_t)NT * KA;             // [2304][832] (early)
    unsigned short* Opart = tail;                            // [4][2304][768] (late)

    hipLaunchKernelGGL(k_prep, dim3(NT + 576 + 9), dim3(256), 0, stream,
                       x, Fu, qF, vF, Wqkv, Wp, Fv, Ax, BqT, WpT);
    hipLaunchKernelGGL((k_gemm64<128, 0, 1>), dim3(TD / 128, NT / 64), dim3(256), 0,
                       stream, Ax, BqT, bqkv, (void*)qkvb, TD, KA, VtG);
    hipLaunchKernelGGL(k_bias, dim3(48, NHEAD, 2), dim3(256), 0, stream,
                       qkvb, rph, rpw, BhG, BwT);
    hipLaunchKernelGGL(k_attn, dim3(NT / 64, NHEAD, NSPLIT), dim3(256), 0, stream,
                       qkvb, VtG, BhG, BwT, Opart, Lpart);
    hipLaunchKernelGGL(k_proj, dim3(DIM / 64, NT / 64), dim3(256), 0, stream,
                       Opart, Lpart, WpT, bp, (float*)d_out);
}

// Round 9
// 189.066 us; speedup vs baseline: 1.0395x; 1.0395x over previous
//
#include <hip/hip_runtime.h>
#include <hip/hip_fp16.h>
#include <hip/hip_bf16.h>

#define NT    2304   // tokens = 48*48
#define DIM   768
#define TD    2304   // 3*dim
#define NHEAD 12
#define HD    64
#define RANK  32
#define KA    832    // augmented K = 768 + 32 (uq) + 32 (uv)
#define NSPLIT 4
#define TILES  9     // 36 / NSPLIT

typedef __attribute__((ext_vector_type(8))) short short8;
typedef __attribute__((ext_vector_type(4))) short short4_t;
typedef __attribute__((ext_vector_type(4))) float floatx4;

__device__ __forceinline__ unsigned short f2bf(float f) {
    union { float f; unsigned u; } v; v.f = f;
    unsigned u = v.u + 0x7FFFu + ((v.u >> 16) & 1u);
    return (unsigned short)(u >> 16);
}
__device__ __forceinline__ float bf2f(unsigned short h) {
    union { unsigned u; float f; } v; v.u = ((unsigned)h) << 16; return v.f;
}
__device__ __forceinline__ float h2f(unsigned short u) {
    __half h = *(__half*)&u; return __half2float(h);
}
__device__ __forceinline__ unsigned pkbf(float a, float b) {   // v_cvt_pk_bf16_f32
    __hip_bfloat162 t = __float22bfloat162_rn(make_float2(a, b));
    unsigned r; __builtin_memcpy(&r, &t, 4); return r;
}
__device__ __forceinline__ void async16(const unsigned short* g, unsigned short* l) {
    __builtin_amdgcn_global_load_lds(
        (const __attribute__((address_space(1))) unsigned int*)g,
        (__attribute__((address_space(3))) unsigned int*)l, 16, 0, 0);
}

// ---------------------------------------------------------------------------
// 64x64 fp32->bf16 transpose tile helper
// ---------------------------------------------------------------------------
__device__ __forceinline__ void tr_tile(const float* __restrict__ src,
                                        unsigned short* __restrict__ dst,
                                        int N, int P, int n0, int k0,
                                        unsigned short* tile, int tid) {
    #pragma unroll
    for (int p = 0; p < 4; ++p) {
        int krow = (tid >> 4) + p * 16, n4 = (tid & 15) * 4;
        float4 v = *(const float4*)(src + (size_t)(k0 + krow) * N + n0 + n4);
        tile[krow * 71 + n4 + 0] = f2bf(v.x);
        tile[krow * 71 + n4 + 1] = f2bf(v.y);
        tile[krow * 71 + n4 + 2] = f2bf(v.z);
        tile[krow * 71 + n4 + 3] = f2bf(v.w);
    }
    __syncthreads();
    #pragma unroll
    for (int p = 0; p < 2; ++p) {
        int c = tid + p * 256;
        int nrow = c >> 3, k8 = (c & 7) * 8;
        short8 o;
        #pragma unroll
        for (int i = 0; i < 8; ++i) o[i] = (short)tile[(k8 + i) * 71 + nrow];
        *(short8*)(dst + (size_t)(n0 + nrow) * P + k0 + k8) = o;
    }
}

// ---------------------------------------------------------------------------
// Fused prep: [0,2304) FacT rows; [2304,2736) Wqkv^T; [2736,2880) Wp^T;
// [2880,2889) Fv fill.
// ---------------------------------------------------------------------------
__global__ __launch_bounds__(256)
void k_prep(const float* __restrict__ x, const float* __restrict__ Fu,
            const float* __restrict__ qF, const float* __restrict__ vF,
            const float* __restrict__ Wqkv, const float* __restrict__ Wp,
            const float* __restrict__ Fv,
            unsigned short* __restrict__ Ax, unsigned short* __restrict__ BqT,
            unsigned short* __restrict__ WpT) {
    __shared__ __align__(16) unsigned short tile[64 * 71];
    int b = blockIdx.x;
    int tid = threadIdx.x;
    if (b < NT) {
        float* part = (float*)tile;            // [8][32]
        float* us = part + 256;                // [32]
        int row = b;
        int r = tid & 31, p = tid >> 5;
        const float* xr = x + (size_t)row * DIM;
        if (tid < 96) {                        // vectorized bf16 cast of x row
            const float4* pp = (const float4*)(xr + tid * 8);
            float4 a = pp[0], bb = pp[1];
            short8 o;
            o[0] = (short)f2bf(a.x);  o[1] = (short)f2bf(a.y);
            o[2] = (short)f2bf(a.z);  o[3] = (short)f2bf(a.w);
            o[4] = (short)f2bf(bb.x); o[5] = (short)f2bf(bb.y);
            o[6] = (short)f2bf(bb.z); o[7] = (short)f2bf(bb.w);
            *(short8*)(Ax + (size_t)row * KA + tid * 8) = o;
        }
        float acc = 0.f;
        int k0 = p * (DIM / 8);
        for (int k = k0; k < k0 + DIM / 8; ++k)
            acc = fmaf(xr[k], Fu[k * RANK + r], acc);
        part[p * 32 + r] = acc;
        __syncthreads();
        if (tid < 32) {
            float s = 0.f;
            #pragma unroll
            for (int pp2 = 0; pp2 < 8; ++pp2) s += part[pp2 * 32 + tid];
            us[tid] = s;
        }
        __syncthreads();
        if (tid < 64) {
            int c = tid & 31;
            const float* F = (tid < 32) ? qF : vF;
            float s = 0.f;
            #pragma unroll
            for (int rr = 0; rr < RANK; ++rr) s = fmaf(us[rr], F[rr * RANK + c], s);
            int col = (tid < 32) ? (768 + c) : (800 + c);
            Ax[(size_t)row * KA + col] = f2bf(s);
        }
    } else if (b < NT + 432) {
        int i = b - NT;
        tr_tile(Wqkv, BqT, TD, KA, (i % 36) * 64, (i / 36) * 64, tile, tid);
    } else if (b < NT + 576) {
        int i = b - NT - 432;
        tr_tile(Wp, WpT, DIM, DIM, (i % 12) * 64, (i / 12) * 64, tile, tid);
    } else {
        int i = b - NT - 576;
        int n = i * 256 + tid;
        unsigned short* d = BqT + (size_t)n * KA;
        #pragma unroll 4
        for (int r = 0; r < 32; ++r) {
            d[768 + r] = (n < 768)   ? f2bf(Fv[r * 768 + n])          : (unsigned short)0;
            d[800 + r] = (n >= 1536) ? f2bf(Fv[r * 768 + (n - 1536)]) : (unsigned short)0;
        }
    }
}

// ---------------------------------------------------------------------------
// bf16 MFMA GEMM, BM=64, BN in {64,128}: C = A @ BT^T + bias. BK=64.
// global_load_lds(16B) staging, XOR-8 swizzle on the global source.
// FUSEV: cols >=1536 also written transposed into VtG[chan][token].
// r7 lesson: 128x128/324-block variant loses on load balance (1.27 blk/CU);
// r8 lesson: fusing the combine into the proj GEMM has no MFMA shadow.
// ---------------------------------------------------------------------------
template<int BN, int OUTF, int FUSEV>
__global__ __launch_bounds__(256)
void k_gemm64(const unsigned short* __restrict__ A,
              const unsigned short* __restrict__ BT,
              const float* __restrict__ bias, void* __restrict__ Cout,
              int N, int K, unsigned short* __restrict__ VtG) {
    __shared__ __align__(16) unsigned short As[64 * 64];
    __shared__ __align__(16) unsigned short Bs[BN * 64];
    constexpr int NJ = BN / 32;
    int tid = threadIdx.x;
    int m0 = blockIdx.y * 64, n0 = blockIdx.x * BN;
    int lane = tid & 63, wave = tid >> 6;
    int wr = wave >> 1, wc = wave & 1;
    int lm = lane & 15, quad = lane >> 4;

    int srow = tid >> 3;                         // 0..31
    int sgrp = ((tid & 7) ^ (srow & 7)) * 8;     // swizzled k-group (global src)
    const unsigned short* gA0 = A + (size_t)(m0 + srow) * K + sgrp;
    const unsigned short* gA1 = A + (size_t)(m0 + 32 + srow) * K + sgrp;
    const unsigned short* gB0 = BT + (size_t)(n0 + srow) * K + sgrp;
    const unsigned short* gB1 = BT + (size_t)(n0 + 32 + srow) * K + sgrp;
    unsigned short* lA0 = As + wave * 512;       // wave-uniform bases
    unsigned short* lA1 = As + 2048 + wave * 512;
    unsigned short* lB0 = Bs + wave * 512;
    unsigned short* lB1 = Bs + 2048 + wave * 512;

    floatx4 acc[2][NJ];
    #pragma unroll
    for (int i = 0; i < 2; ++i)
        #pragma unroll
        for (int j = 0; j < NJ; ++j) acc[i][j] = (floatx4){0.f, 0.f, 0.f, 0.f};

    for (int kt = 0; kt < K; kt += 64) {
        async16(gA0 + kt, lA0);
        async16(gA1 + kt, lA1);
        async16(gB0 + kt, lB0);
        async16(gB1 + kt, lB1);
        if constexpr (BN == 128) {
            const unsigned short* gB2 = BT + (size_t)(n0 + 64 + srow) * K + sgrp;
            const unsigned short* gB3 = BT + (size_t)(n0 + 96 + srow) * K + sgrp;
            async16(gB2 + kt, Bs + 4096 + wave * 512);
            async16(gB3 + kt, Bs + 6144 + wave * 512);
        }
        __syncthreads();
        #pragma unroll
        for (int kk = 0; kk < 2; ++kk) {
            short8 af[2];
            #pragma unroll
            for (int t2 = 0; t2 < 2; ++t2) {
                int row = wr * 32 + t2 * 16 + lm;
                int g = kk * 4 + quad;
                af[t2] = *(const short8*)(As + row * 64 + ((g ^ (row & 7)) * 8));
            }
            #pragma unroll
            for (int j = 0; j < NJ; ++j) {
                int row = wc * (BN / 2) + j * 16 + lm;
                int g = kk * 4 + quad;
                short8 bq = *(const short8*)(Bs + row * 64 + ((g ^ (row & 7)) * 8));
                acc[0][j] = __builtin_amdgcn_mfma_f32_16x16x32_bf16(af[0], bq, acc[0][j], 0, 0, 0);
                acc[1][j] = __builtin_amdgcn_mfma_f32_16x16x32_bf16(af[1], bq, acc[1][j], 0, 0, 0);
            }
        }
        __syncthreads();
    }

    #pragma unroll
    for (int jt = 0; jt < NJ; ++jt) {
        int col = n0 + wc * (BN / 2) + jt * 16 + lm;
        float bv = bias[col];
        #pragma unroll
        for (int it = 0; it < 2; ++it) {
            int rowb = m0 + wr * 32 + it * 16 + quad * 4;
            #pragma unroll
            for (int r = 0; r < 4; ++r) {
                float val = acc[it][jt][r] + bv;
                if (OUTF)
                    ((float*)Cout)[(size_t)(rowb + r) * N + col] = val;
                else
                    ((unsigned short*)Cout)[(size_t)(rowb + r) * N + col] = f2bf(val);
            }
            if (FUSEV && col >= 1536) {
                short4_t vt;
                #pragma unroll
                for (int r = 0; r < 4; ++r) vt[r] = (short)f2bf(acc[it][jt][r] + bv);
                *(short4_t*)(VtG + (size_t)(col - 1536) * NT + rowb) = vt;
            }
        }
    }
}

// ---------------------------------------------------------------------------
// Rel-pos bias tables via MFMA. Stored as half, pre-multiplied by log2(e).
//   which=0: BhG[h][j][t]   (j = key h-coord)
//   which=1: BwT[h][t][j]   (j = key w-coord)  -- TRANSPOSED layout
// ---------------------------------------------------------------------------
__global__ __launch_bounds__(256)
void k_bias(const unsigned short* __restrict__ qkv, const float* __restrict__ rph,
            const float* __restrict__ rpw, unsigned short* __restrict__ BhG,
            unsigned short* __restrict__ BwT) {
    __shared__ __align__(16) unsigned short Qs[48 * 68];
    __shared__ __align__(16) unsigned short Ts[48 * 68];
    int tid = threadIdx.x;
    int pos = blockIdx.x, h = blockIdx.y, which = blockIdx.z;
    const float* tab = which ? rpw : rph;
    for (int idx = tid; idx < 48 * 8; idx += 256) {
        int row = idx >> 3, c8 = (idx & 7) * 8;
        int t = which ? (row * 48 + pos) : (pos * 48 + row);
        *(short8*)(Qs + row * 68 + c8) =
            *(const short8*)(qkv + (size_t)t * TD + h * HD + c8);
    }
    for (int idx = tid; idx < 48 * 8; idx += 256) {
        int j = idx >> 3, c8 = (idx & 7) * 8;
        const float* src = tab + (size_t)(pos + 47 - j) * HD + c8;
        short8 o;
        #pragma unroll
        for (int i = 0; i < 8; ++i) o[i] = (short)f2bf(src[i]);
        *(short8*)(Ts + j * 68 + c8) = o;
    }
    __syncthreads();
    int lane = tid & 63, wave = tid >> 6;
    int lm = lane & 15, quad = lane >> 4;
    for (int tt = wave; tt < 9; tt += 4) {
        int rt = tt / 3, jt = tt - rt * 3;
        floatx4 acc = (floatx4){0.f, 0.f, 0.f, 0.f};
        #pragma unroll
        for (int kt = 0; kt < 2; ++kt) {
            short8 a = *(const short8*)(Qs + (rt * 16 + lm) * 68 + kt * 32 + quad * 8);
            short8 bb = *(const short8*)(Ts + (jt * 16 + lm) * 68 + kt * 32 + quad * 8);
            acc = __builtin_amdgcn_mfma_f32_16x16x32_bf16(a, bb, acc, 0, 0, 0);
        }
        int j = jt * 16 + lm;
        int r0 = rt * 16 + quad * 4;
        if (which == 0) {
            short4_t o;
            #pragma unroll
            for (int r = 0; r < 4; ++r) {
                __half hh = __float2half(acc[r] * 1.44269504f);
                o[r] = *(short*)&hh;
            }
            *(short4_t*)(BhG + (size_t)(h * 48 + j) * NT + pos * 48 + r0) = o;
        } else {
            #pragma unroll
            for (int r = 0; r < 4; ++r) {
                __half hh = __float2half(acc[r] * 1.44269504f);
                int t = (r0 + r) * 48 + pos;
                BwT[((size_t)h * NT + t) * 48 + j] = *(unsigned short*)&hh;
            }
        }
    }
}

// ---------------------------------------------------------------------------
// MFMA flash attention, 4-way key split, S^T layout. ROUND-3 STRUCTURE
// (session best, 48.6 us): 2 barriers/tile, register K/V double-buffer,
// separate Ps buffer, swizzled stride-64 tiles, LDS 32640 B -> 5 blocks/CU.
// Survived 8 rounds of directed attacks (occupancy both directions, grid
// generations, XCD locality, fusion) — all regressed vs this form.
// ---------------------------------------------------------------------------
__global__ __launch_bounds__(256, 5)
void k_attn(const unsigned short* __restrict__ qkv,
            const unsigned short* __restrict__ VtG,
            const unsigned short* __restrict__ BhG,
            const unsigned short* __restrict__ BwT,
            unsigned short* __restrict__ Opart, float* __restrict__ Lpart) {
    __shared__ __align__(16) unsigned short Ks[64 * 64];   // K tile (swizzled)
    __shared__ __align__(16) unsigned short Vts[64 * 64];  // V^T tile (swizzled)
    __shared__ __align__(16) unsigned short Ps[64 * 64];   // Q stage, then P (swizzled)
    __shared__ __align__(16) unsigned short BhS[12 * 64];  // [hj_local][qrow] half
    __shared__ __align__(16) unsigned short BwS[64 * 48];  // [qrow][wj] half

    int tid = threadIdx.x;
    int lane = tid & 63, wave = tid >> 6;
    int lm = lane & 15, quad = lane >> 4;
    int i0 = blockIdx.x * 64, h = blockIdx.y, z = blockIdx.z;
    int qrow = wave * 16 + lm;                   // this lane's q-row (local)
    int j0 = z * TILES * 64;

    int row0 = tid >> 3, cc0 = (tid & 7) * 8;
    int row1 = row0 + 32;
    int sw0 = row0 * 64 + (((tid & 7) ^ (row0 & 7)) << 3);
    int sw1 = row1 * 64 + (((tid & 7) ^ (row1 & 7)) << 3);

    // stage Q into Ps (swizzled), then read fragments
    *(short8*)(Ps + sw0) =
        *(const short8*)(qkv + (size_t)(i0 + row0) * TD + h * HD + cc0);
    *(short8*)(Ps + sw1) =
        *(const short8*)(qkv + (size_t)(i0 + row1) * TD + h * HD + cc0);
    __syncthreads();
    short8 qf[2];
    qf[0] = *(const short8*)(Ps + qrow * 64 + ((quad ^ (qrow & 7)) << 3));
    qf[1] = *(const short8*)(Ps + qrow * 64 + (((4 + quad) ^ (qrow & 7)) << 3));

    // stage bias tables: BhS only 12 local hj rows [hj][qrow]; BwS [qrow][wj]
    if (tid < 192) {
        int j = tid >> 4, r4 = (tid & 15) * 4;
        *(short4_t*)(BhS + j * 64 + r4) =
            *(const short4_t*)(BhG + (size_t)(h * 48 + z * 12 + j) * NT + i0 + r4);
    }
    for (int idx = tid; idx < 64 * 6; idx += 256) {
        int row = idx / 6, c8 = (idx - row * 6) * 8;
        *(short8*)(BwS + row * 48 + c8) =
            *(const short8*)(BwT + ((size_t)h * NT + i0 + row) * 48 + c8);
    }

    // register double-buffer of K/V rows
    const unsigned short* gK = qkv + (size_t)(j0 + row0) * TD + 768 + h * HD + cc0;
    const unsigned short* gV = VtG + (size_t)(h * HD + row0) * NT + j0 + cc0;
    short8 kr0 = *(const short8*)gK;
    short8 kr1 = *(const short8*)(gK + (size_t)32 * TD);
    short8 vr0 = *(const short8*)gV;
    short8 vr1 = *(const short8*)(gV + (size_t)32 * NT);

    floatx4 o_acc[4];
    float lp = 0.f;
    #pragma unroll
    for (int nt = 0; nt < 4; ++nt) o_acc[nt] = (floatx4){0.f, 0.f, 0.f, 0.f};

    for (int t = 0; t < TILES; ++t) {
        *(short8*)(Ks + sw0) = kr0;
        *(short8*)(Ks + sw1) = kr1;
        *(short8*)(Vts + sw0) = vr0;
        *(short8*)(Vts + sw1) = vr1;
        __syncthreads();                         // staging visible (+Q/bias on t=0)

        // S^T = K Q^T  (A = K-frag, B = Q-frag)
        floatx4 s_acc[4];
        #pragma unroll
        for (int nt = 0; nt < 4; ++nt) s_acc[nt] = (floatx4){0.f, 0.f, 0.f, 0.f};
        #pragma unroll
        for (int kt = 0; kt < 2; ++kt)
            #pragma unroll
            for (int nt = 0; nt < 4; ++nt) {
                int row = nt * 16 + lm;
                short8 kf = *(const short8*)(Ks + row * 64 + (((kt * 4 + quad) ^ (row & 7)) << 3));
                s_acc[nt] = __builtin_amdgcn_mfma_f32_16x16x32_bf16(
                    kf, qf[kt], s_acc[nt], 0, 0, 0);
            }

        // prefetch next tile K/V into registers (hides under epilogue/PV)
        if (t + 1 < TILES) {
            gK += 64 * TD; gV += 64;
            kr0 = *(const short8*)gK;
            kr1 = *(const short8*)(gK + (size_t)32 * TD);
            vr0 = *(const short8*)gV;
            vr1 = *(const short8*)(gV + (size_t)32 * NT);
        }

        // epilogue: lane owns keys nt*16+quad*4..+3 for its single q-row
        int base = t * 64 + quad * 4;            // split-local key index
        int hj0 = base / 48;
        int wjb = base - hj0 * 48;
        #pragma unroll
        for (int nt = 0; nt < 4; ++nt) {
            int wj = wjb + nt * 16;
            int hj = hj0 + (wj >= 48 ? 1 : 0);   // local hj in [0,12)
            wj -= (wj >= 48 ? 48 : 0);
            float bh = h2f(BhS[hj * 64 + qrow]);
            short4_t bw4 = *(const short4_t*)(BwS + qrow * 48 + wj);
            float pe[4];
            #pragma unroll
            for (int r = 0; r < 4; ++r) {
                float b = bh + h2f((unsigned short)bw4[r]);
                pe[r] = exp2f(fmaf(0.18033688f, s_acc[nt][r], b));
                lp += pe[r];
            }
            union { unsigned u[2]; short4_t s; } pk;
            pk.u[0] = pkbf(pe[0], pe[1]);
            pk.u[1] = pkbf(pe[2], pe[3]);
            int c = nt * 16 + quad * 4;
            *(short4_t*)(Ps + qrow * 64 + (((c >> 3) ^ (qrow & 7)) << 3)
                         + ((quad & 1) << 2)) = pk.s;
        }

        // O += P V : pf from wave-private Ps rows, vf from Vts
        #pragma unroll
        for (int kt = 0; kt < 2; ++kt) {
            short8 pf = *(const short8*)(Ps + qrow * 64 + (((kt * 4 + quad) ^ (qrow & 7)) << 3));
            #pragma unroll
            for (int nt = 0; nt < 4; ++nt) {
                int row = nt * 16 + lm;
                short8 vf = *(const short8*)(Vts + row * 64 + (((kt * 4 + quad) ^ (row & 7)) << 3));
                o_acc[nt] = __builtin_amdgcn_mfma_f32_16x16x32_bf16(
                    pf, vf, o_acc[nt], 0, 0, 0);
            }
        }
        __syncthreads();                         // K/V consumed: next stage safe
    }

    // row sums: lane holds partial for its q-row over its quad's keys
    lp += __shfl_xor(lp, 16);
    lp += __shfl_xor(lp, 32);
    if (quad == 0)
        Lpart[((size_t)z * NHEAD + h) * NT + i0 + qrow] = lp;

    unsigned short* op = Opart + (size_t)z * NT * DIM;
    #pragma unroll
    for (int nt = 0; nt < 4; ++nt)
        #pragma unroll
        for (int r = 0; r < 4; ++r)
            op[(size_t)(i0 + wave * 16 + quad * 4 + r) * DIM + h * HD + nt * 16 + lm]
                = f2bf(o_acc[nt][r]);
}

// ---------------------------------------------------------------------------
// Combine splits
// ---------------------------------------------------------------------------
__global__ __launch_bounds__(256)
void k_comb(const unsigned short* __restrict__ Opart, const float* __restrict__ Lpart,
            unsigned short* __restrict__ aob) {
    int gid = blockIdx.x * 256 + threadIdx.x;
    int t = gid / 96, c8 = (gid - t * 96) * 8;
    int h = c8 >> 6;
    float l = 0.f;
    #pragma unroll
    for (int s = 0; s < NSPLIT; ++s)
        l += Lpart[((size_t)s * NHEAD + h) * NT + t];
    float inv = 1.f / l;
    float acc[8] = {0, 0, 0, 0, 0, 0, 0, 0};
    #pragma unroll
    for (int s = 0; s < NSPLIT; ++s) {
        short8 v = *(const short8*)(Opart + (size_t)s * NT * DIM + (size_t)t * DIM + c8);
        #pragma unroll
        for (int i = 0; i < 8; ++i) acc[i] += bf2f((unsigned short)v[i]);
    }
    union { unsigned u[4]; short8 s; } o;
    #pragma unroll
    for (int i = 0; i < 4; ++i) o.u[i] = pkbf(acc[2 * i] * inv, acc[2 * i + 1] * inv);
    *(short8*)(aob + (size_t)t * DIM + c8) = o.s;
}

// ---------------------------------------------------------------------------
extern "C" void kernel_launch(void* const* d_in, const int* in_sizes, int n_in,
                              void* d_out, int out_size, void* d_ws, size_t ws_size,
                              hipStream_t stream) {
    const float* x    = (const float*)d_in[0];
    const float* Wqkv = (const float*)d_in[1];
    const float* bqkv = (const float*)d_in[2];
    const float* Fu   = (const float*)d_in[3];
    const float* Fv   = (const float*)d_in[4];
    const float* qF   = (const float*)d_in[5];
    const float* vF   = (const float*)d_in[6];
    const float* rph  = (const float*)d_in[7];
    const float* rpw  = (const float*)d_in[8];
    const float* Wp   = (const float*)d_in[9];
    const float* bp   = (const float*)d_in[10];

    unsigned short* ws   = (unsigned short*)d_ws;
    unsigned short* qkvb = ws;                               // [2304][2304]
    unsigned short* aob  = qkvb;                             // alias: qkvb dead post-attn
    unsigned short* WpT  = qkvb + (size_t)NT * TD;           // [768][768]
    unsigned short* VtG  = WpT  + (size_t)DIM * DIM;         // [768][2304]
    unsigned short* BhG  = VtG  + (size_t)DIM * NT;          // [12][48][2304] half
    unsigned short* BwT  = BhG  + (size_t)NHEAD * 48 * NT;   // [12][2304][48] half
    float*          Lpart = (float*)(BwT + (size_t)NHEAD * NT * 48); // [4][12][2304]
    unsigned short* tail = (unsigned short*)(Lpart + (size_t)NSPLIT * NHEAD * NT);
    unsigned short* Ax   = tail;                             // [2304][832] (early)
    unsigned short* BqT  = Ax + (size_t)NT * KA;             // [2304][832] (early)
    unsigned short* Opart = tail;                            // [4][2304][768] (late)

    hipLaunchKernelGGL(k_prep, dim3(NT + 576 + 9), dim3(256), 0, stream,
                       x, Fu, qF, vF, Wqkv, Wp, Fv, Ax, BqT, WpT);
    hipLaunchKernelGGL((k_gemm64<128, 0, 1>), dim3(TD / 128, NT / 64), dim3(256), 0,
                       stream, Ax, BqT, bqkv, (void*)qkvb, TD, KA, VtG);
    hipLaunchKernelGGL(k_bias, dim3(48, NHEAD, 2), dim3(256), 0, stream,
                       qkvb, rph, rpw, BhG, BwT);
    hipLaunchKernelGGL(k_attn, dim3(NT / 64, NHEAD, NSPLIT), dim3(256), 0, stream,
                       qkvb, VtG, BhG, BwT, Opart, Lpart);
    hipLaunchKernelGGL(k_comb, dim3(NT * 96 / 256), dim3(256), 0, stream,
                       Opart, Lpart, aob);
    hipLaunchKernelGGL((k_gemm64<64, 1, 0>), dim3(DIM / 64, NT / 64), dim3(256), 0,
                       stream, aob, WpT, bp, d_out, DIM, DIM, (unsigned short*)nullptr);
}

// Round 10
// 187.577 us; speedup vs baseline: 1.0478x; 1.0079x over previous
//
#include <hip/hip_runtime.h>
#include <hip/hip_fp16.h>
#include <hip/hip_bf16.h>

#define NT    2304   // tokens = 48*48
#define DIM   768
#define TD    2304   // 3*dim
#define NHEAD 12
#define HD    64
#define RANK  32
#define KA    832    // augmented K = 768 + 32 (uq) + 32 (uv)
#define NSPLIT 4
#define TILES  9     // 36 / NSPLIT

typedef __attribute__((ext_vector_type(8))) short short8;
typedef __attribute__((ext_vector_type(4))) short short4_t;
typedef __attribute__((ext_vector_type(4))) float floatx4;

__device__ __forceinline__ unsigned short f2bf(float f) {
    union { float f; unsigned u; } v; v.f = f;
    unsigned u = v.u + 0x7FFFu + ((v.u >> 16) & 1u);
    return (unsigned short)(u >> 16);
}
__device__ __forceinline__ float bf2f(unsigned short h) {
    union { unsigned u; float f; } v; v.u = ((unsigned)h) << 16; return v.f;
}
__device__ __forceinline__ float h2f(unsigned short u) {
    __half h = *(__half*)&u; return __half2float(h);
}
__device__ __forceinline__ unsigned pkbf(float a, float b) {   // v_cvt_pk_bf16_f32
    __hip_bfloat162 t = __float22bfloat162_rn(make_float2(a, b));
    unsigned r; __builtin_memcpy(&r, &t, 4); return r;
}
__device__ __forceinline__ void async16(const unsigned short* g, unsigned short* l) {
    __builtin_amdgcn_global_load_lds(
        (const __attribute__((address_space(1))) unsigned int*)g,
        (__attribute__((address_space(3))) unsigned int*)l, 16, 0, 0);
}

// ---------------------------------------------------------------------------
// 64x64 fp32->bf16 transpose tile helper
// ---------------------------------------------------------------------------
__device__ __forceinline__ void tr_tile(const float* __restrict__ src,
                                        unsigned short* __restrict__ dst,
                                        int N, int P, int n0, int k0,
                                        unsigned short* tile, int tid) {
    #pragma unroll
    for (int p = 0; p < 4; ++p) {
        int krow = (tid >> 4) + p * 16, n4 = (tid & 15) * 4;
        float4 v = *(const float4*)(src + (size_t)(k0 + krow) * N + n0 + n4);
        tile[krow * 71 + n4 + 0] = f2bf(v.x);
        tile[krow * 71 + n4 + 1] = f2bf(v.y);
        tile[krow * 71 + n4 + 2] = f2bf(v.z);
        tile[krow * 71 + n4 + 3] = f2bf(v.w);
    }
    __syncthreads();
    #pragma unroll
    for (int p = 0; p < 2; ++p) {
        int c = tid + p * 256;
        int nrow = c >> 3, k8 = (c & 7) * 8;
        short8 o;
        #pragma unroll
        for (int i = 0; i < 8; ++i) o[i] = (short)tile[(k8 + i) * 71 + nrow];
        *(short8*)(dst + (size_t)(n0 + nrow) * P + k0 + k8) = o;
    }
}

// ---------------------------------------------------------------------------
// Fused prep, HEAVY-FIRST block order (LPT scheduling: the 585 transpose/
// fill blocks run first so their cost hides under the 2304 cheap FacT rows
// instead of forming the kernel's tail):
//   [0,432) Wqkv^T tiles; [432,576) Wp^T tiles; [576,585) Fv fill;
//   [585, 585+NT) FacT rows.
// ---------------------------------------------------------------------------
__global__ __launch_bounds__(256)
void k_prep(const float* __restrict__ x, const float* __restrict__ Fu,
            const float* __restrict__ qF, const float* __restrict__ vF,
            const float* __restrict__ Wqkv, const float* __restrict__ Wp,
            const float* __restrict__ Fv,
            unsigned short* __restrict__ Ax, unsigned short* __restrict__ BqT,
            unsigned short* __restrict__ WpT) {
    __shared__ __align__(16) unsigned short tile[64 * 71];
    int b = blockIdx.x;
    int tid = threadIdx.x;
    if (b < 432) {
        tr_tile(Wqkv, BqT, TD, KA, (b % 36) * 64, (b / 36) * 64, tile, tid);
    } else if (b < 576) {
        int i = b - 432;
        tr_tile(Wp, WpT, DIM, DIM, (i % 12) * 64, (i / 12) * 64, tile, tid);
    } else if (b < 585) {
        int i = b - 576;
        int n = i * 256 + tid;
        unsigned short* d = BqT + (size_t)n * KA;
        #pragma unroll 4
        for (int r = 0; r < 32; ++r) {
            d[768 + r] = (n < 768)   ? f2bf(Fv[r * 768 + n])          : (unsigned short)0;
            d[800 + r] = (n >= 1536) ? f2bf(Fv[r * 768 + (n - 1536)]) : (unsigned short)0;
        }
    } else {
        float* part = (float*)tile;            // [8][32]
        float* us = part + 256;                // [32]
        int row = b - 585;
        int r = tid & 31, p = tid >> 5;
        const float* xr = x + (size_t)row * DIM;
        if (tid < 96) {                        // vectorized bf16 cast of x row
            const float4* pp = (const float4*)(xr + tid * 8);
            float4 a = pp[0], bb = pp[1];
            short8 o;
            o[0] = (short)f2bf(a.x);  o[1] = (short)f2bf(a.y);
            o[2] = (short)f2bf(a.z);  o[3] = (short)f2bf(a.w);
            o[4] = (short)f2bf(bb.x); o[5] = (short)f2bf(bb.y);
            o[6] = (short)f2bf(bb.z); o[7] = (short)f2bf(bb.w);
            *(short8*)(Ax + (size_t)row * KA + tid * 8) = o;
        }
        float acc = 0.f;
        int k0 = p * (DIM / 8);
        for (int k = k0; k < k0 + DIM / 8; ++k)
            acc = fmaf(xr[k], Fu[k * RANK + r], acc);
        part[p * 32 + r] = acc;
        __syncthreads();
        if (tid < 32) {
            float s = 0.f;
            #pragma unroll
            for (int pp2 = 0; pp2 < 8; ++pp2) s += part[pp2 * 32 + tid];
            us[tid] = s;
        }
        __syncthreads();
        if (tid < 64) {
            int c = tid & 31;
            const float* F = (tid < 32) ? qF : vF;
            float s = 0.f;
            #pragma unroll
            for (int rr = 0; rr < RANK; ++rr) s = fmaf(us[rr], F[rr * RANK + c], s);
            int col = (tid < 32) ? (768 + c) : (800 + c);
            Ax[(size_t)row * KA + col] = f2bf(s);
        }
    }
}

// ---------------------------------------------------------------------------
// bf16 MFMA GEMM, BM=64, BN in {64,128}: C = A @ BT^T + bias. BK=64.
// global_load_lds(16B) staging, XOR-8 swizzle on the global source.
// FUSEV: cols >=1536 also written transposed into VtG[chan][token].
// r7 lesson: 128x128/324-block variant loses on load balance (1.27 blk/CU);
// r8 lesson: fusing the combine into the proj GEMM has no MFMA shadow.
// ---------------------------------------------------------------------------
template<int BN, int OUTF, int FUSEV>
__global__ __launch_bounds__(256)
void k_gemm64(const unsigned short* __restrict__ A,
              const unsigned short* __restrict__ BT,
              const float* __restrict__ bias, void* __restrict__ Cout,
              int N, int K, unsigned short* __restrict__ VtG) {
    __shared__ __align__(16) unsigned short As[64 * 64];
    __shared__ __align__(16) unsigned short Bs[BN * 64];
    constexpr int NJ = BN / 32;
    int tid = threadIdx.x;
    int m0 = blockIdx.y * 64, n0 = blockIdx.x * BN;
    int lane = tid & 63, wave = tid >> 6;
    int wr = wave >> 1, wc = wave & 1;
    int lm = lane & 15, quad = lane >> 4;

    int srow = tid >> 3;                         // 0..31
    int sgrp = ((tid & 7) ^ (srow & 7)) * 8;     // swizzled k-group (global src)
    const unsigned short* gA0 = A + (size_t)(m0 + srow) * K + sgrp;
    const unsigned short* gA1 = A + (size_t)(m0 + 32 + srow) * K + sgrp;
    const unsigned short* gB0 = BT + (size_t)(n0 + srow) * K + sgrp;
    const unsigned short* gB1 = BT + (size_t)(n0 + 32 + srow) * K + sgrp;
    unsigned short* lA0 = As + wave * 512;       // wave-uniform bases
    unsigned short* lA1 = As + 2048 + wave * 512;
    unsigned short* lB0 = Bs + wave * 512;
    unsigned short* lB1 = Bs + 2048 + wave * 512;

    floatx4 acc[2][NJ];
    #pragma unroll
    for (int i = 0; i < 2; ++i)
        #pragma unroll
        for (int j = 0; j < NJ; ++j) acc[i][j] = (floatx4){0.f, 0.f, 0.f, 0.f};

    for (int kt = 0; kt < K; kt += 64) {
        async16(gA0 + kt, lA0);
        async16(gA1 + kt, lA1);
        async16(gB0 + kt, lB0);
        async16(gB1 + kt, lB1);
        if constexpr (BN == 128) {
            const unsigned short* gB2 = BT + (size_t)(n0 + 64 + srow) * K + sgrp;
            const unsigned short* gB3 = BT + (size_t)(n0 + 96 + srow) * K + sgrp;
            async16(gB2 + kt, Bs + 4096 + wave * 512);
            async16(gB3 + kt, Bs + 6144 + wave * 512);
        }
        __syncthreads();
        #pragma unroll
        for (int kk = 0; kk < 2; ++kk) {
            short8 af[2];
            #pragma unroll
            for (int t2 = 0; t2 < 2; ++t2) {
                int row = wr * 32 + t2 * 16 + lm;
                int g = kk * 4 + quad;
                af[t2] = *(const short8*)(As + row * 64 + ((g ^ (row & 7)) * 8));
            }
            #pragma unroll
            for (int j = 0; j < NJ; ++j) {
                int row = wc * (BN / 2) + j * 16 + lm;
                int g = kk * 4 + quad;
                short8 bq = *(const short8*)(Bs + row * 64 + ((g ^ (row & 7)) * 8));
                acc[0][j] = __builtin_amdgcn_mfma_f32_16x16x32_bf16(af[0], bq, acc[0][j], 0, 0, 0);
                acc[1][j] = __builtin_amdgcn_mfma_f32_16x16x32_bf16(af[1], bq, acc[1][j], 0, 0, 0);
            }
        }
        __syncthreads();
    }

    #pragma unroll
    for (int jt = 0; jt < NJ; ++jt) {
        int col = n0 + wc * (BN / 2) + jt * 16 + lm;
        float bv = bias[col];
        #pragma unroll
        for (int it = 0; it < 2; ++it) {
            int rowb = m0 + wr * 32 + it * 16 + quad * 4;
            #pragma unroll
            for (int r = 0; r < 4; ++r) {
                float val = acc[it][jt][r] + bv;
                if (OUTF)
                    ((float*)Cout)[(size_t)(rowb + r) * N + col] = val;
                else
                    ((unsigned short*)Cout)[(size_t)(rowb + r) * N + col] = f2bf(val);
            }
            if (FUSEV && col >= 1536) {
                short4_t vt;
                #pragma unroll
                for (int r = 0; r < 4; ++r) vt[r] = (short)f2bf(acc[it][jt][r] + bv);
                *(short4_t*)(VtG + (size_t)(col - 1536) * NT + rowb) = vt;
            }
        }
    }
}

// ---------------------------------------------------------------------------
// Rel-pos bias tables via MFMA. Stored as half, pre-multiplied by log2(e).
//   which=0: BhG[h][j][t]   (j = key h-coord)
//   which=1: BwT[h][t][j]   (j = key w-coord)  -- TRANSPOSED layout
// ---------------------------------------------------------------------------
__global__ __launch_bounds__(256)
void k_bias(const unsigned short* __restrict__ qkv, const float* __restrict__ rph,
            const float* __restrict__ rpw, unsigned short* __restrict__ BhG,
            unsigned short* __restrict__ BwT) {
    __shared__ __align__(16) unsigned short Qs[48 * 68];
    __shared__ __align__(16) unsigned short Ts[48 * 68];
    int tid = threadIdx.x;
    int pos = blockIdx.x, h = blockIdx.y, which = blockIdx.z;
    const float* tab = which ? rpw : rph;
    for (int idx = tid; idx < 48 * 8; idx += 256) {
        int row = idx >> 3, c8 = (idx & 7) * 8;
        int t = which ? (row * 48 + pos) : (pos * 48 + row);
        *(short8*)(Qs + row * 68 + c8) =
            *(const short8*)(qkv + (size_t)t * TD + h * HD + c8);
    }
    for (int idx = tid; idx < 48 * 8; idx += 256) {
        int j = idx >> 3, c8 = (idx & 7) * 8;
        const float* src = tab + (size_t)(pos + 47 - j) * HD + c8;
        short8 o;
        #pragma unroll
        for (int i = 0; i < 8; ++i) o[i] = (short)f2bf(src[i]);
        *(short8*)(Ts + j * 68 + c8) = o;
    }
    __syncthreads();
    int lane = tid & 63, wave = tid >> 6;
    int lm = lane & 15, quad = lane >> 4;
    for (int tt = wave; tt < 9; tt += 4) {
        int rt = tt / 3, jt = tt - rt * 3;
        floatx4 acc = (floatx4){0.f, 0.f, 0.f, 0.f};
        #pragma unroll
        for (int kt = 0; kt < 2; ++kt) {
            short8 a = *(const short8*)(Qs + (rt * 16 + lm) * 68 + kt * 32 + quad * 8);
            short8 bb = *(const short8*)(Ts + (jt * 16 + lm) * 68 + kt * 32 + quad * 8);
            acc = __builtin_amdgcn_mfma_f32_16x16x32_bf16(a, bb, acc, 0, 0, 0);
        }
        int j = jt * 16 + lm;
        int r0 = rt * 16 + quad * 4;
        if (which == 0) {
            short4_t o;
            #pragma unroll
            for (int r = 0; r < 4; ++r) {
                __half hh = __float2half(acc[r] * 1.44269504f);
                o[r] = *(short*)&hh;
            }
            *(short4_t*)(BhG + (size_t)(h * 48 + j) * NT + pos * 48 + r0) = o;
        } else {
            #pragma unroll
            for (int r = 0; r < 4; ++r) {
                __half hh = __float2half(acc[r] * 1.44269504f);
                int t = (r0 + r) * 48 + pos;
                BwT[((size_t)h * NT + t) * 48 + j] = *(unsigned short*)&hh;
            }
        }
    }
}

// ---------------------------------------------------------------------------
// MFMA flash attention, 4-way key split, S^T layout. ROUND-3 STRUCTURE
// (session best): 2 barriers/tile, register K/V double-buffer, separate
// Ps buffer, swizzled stride-64 tiles, LDS 32640 B -> 5 blocks/CU.
// r10 change: the 14 loop-invariant swizzled LDS offsets are hoisted into
// registers (at VGPR=48 the compiler recomputed them every tile under
// pressure; __launch_bounds__(256,5) allows up to 102 VGPRs).
// ---------------------------------------------------------------------------
__global__ __launch_bounds__(256, 5)
void k_attn(const unsigned short* __restrict__ qkv,
            const unsigned short* __restrict__ VtG,
            const unsigned short* __restrict__ BhG,
            const unsigned short* __restrict__ BwT,
            unsigned short* __restrict__ Opart, float* __restrict__ Lpart) {
    __shared__ __align__(16) unsigned short Ks[64 * 64];   // K tile (swizzled)
    __shared__ __align__(16) unsigned short Vts[64 * 64];  // V^T tile (swizzled)
    __shared__ __align__(16) unsigned short Ps[64 * 64];   // Q stage, then P (swizzled)
    __shared__ __align__(16) unsigned short BhS[12 * 64];  // [hj_local][qrow] half
    __shared__ __align__(16) unsigned short BwS[64 * 48];  // [qrow][wj] half

    int tid = threadIdx.x;
    int lane = tid & 63, wave = tid >> 6;
    int lm = lane & 15, quad = lane >> 4;
    int i0 = blockIdx.x * 64, h = blockIdx.y, z = blockIdx.z;
    int qrow = wave * 16 + lm;                   // this lane's q-row (local)
    int j0 = z * TILES * 64;

    int row0 = tid >> 3, cc0 = (tid & 7) * 8;
    int row1 = row0 + 32;
    int sw0 = row0 * 64 + (((tid & 7) ^ (row0 & 7)) << 3);
    int sw1 = row1 * 64 + (((tid & 7) ^ (row1 & 7)) << 3);

    // stage Q into Ps (swizzled), then read fragments
    *(short8*)(Ps + sw0) =
        *(const short8*)(qkv + (size_t)(i0 + row0) * TD + h * HD + cc0);
    *(short8*)(Ps + sw1) =
        *(const short8*)(qkv + (size_t)(i0 + row1) * TD + h * HD + cc0);
    __syncthreads();
    short8 qf[2];
    qf[0] = *(const short8*)(Ps + qrow * 64 + ((quad ^ (qrow & 7)) << 3));
    qf[1] = *(const short8*)(Ps + qrow * 64 + (((4 + quad) ^ (qrow & 7)) << 3));

    // hoisted loop-invariant swizzled LDS offsets (statically indexed)
    int rdoff[2][4], poff[2], pwoff[4];
    #pragma unroll
    for (int kt = 0; kt < 2; ++kt) {
        poff[kt] = qrow * 64 + (((kt * 4 + quad) ^ (qrow & 7)) << 3);
        #pragma unroll
        for (int nt = 0; nt < 4; ++nt) {
            int row = nt * 16 + lm;
            rdoff[kt][nt] = row * 64 + (((kt * 4 + quad) ^ (row & 7)) << 3);
        }
    }
    #pragma unroll
    for (int nt = 0; nt < 4; ++nt) {
        int c = nt * 16 + quad * 4;
        pwoff[nt] = qrow * 64 + (((c >> 3) ^ (qrow & 7)) << 3) + ((quad & 1) << 2);
    }

    // stage bias tables: BhS only 12 local hj rows [hj][qrow]; BwS [qrow][wj]
    if (tid < 192) {
        int j = tid >> 4, r4 = (tid & 15) * 4;
        *(short4_t*)(BhS + j * 64 + r4) =
            *(const short4_t*)(BhG + (size_t)(h * 48 + z * 12 + j) * NT + i0 + r4);
    }
    for (int idx = tid; idx < 64 * 6; idx += 256) {
        int row = idx / 6, c8 = (idx - row * 6) * 8;
        *(short8*)(BwS + row * 48 + c8) =
            *(const short8*)(BwT + ((size_t)h * NT + i0 + row) * 48 + c8);
    }

    // register double-buffer of K/V rows
    const unsigned short* gK = qkv + (size_t)(j0 + row0) * TD + 768 + h * HD + cc0;
    const unsigned short* gV = VtG + (size_t)(h * HD + row0) * NT + j0 + cc0;
    short8 kr0 = *(const short8*)gK;
    short8 kr1 = *(const short8*)(gK + (size_t)32 * TD);
    short8 vr0 = *(const short8*)gV;
    short8 vr1 = *(const short8*)(gV + (size_t)32 * NT);

    floatx4 o_acc[4];
    float lp = 0.f;
    #pragma unroll
    for (int nt = 0; nt < 4; ++nt) o_acc[nt] = (floatx4){0.f, 0.f, 0.f, 0.f};

    for (int t = 0; t < TILES; ++t) {
        *(short8*)(Ks + sw0) = kr0;
        *(short8*)(Ks + sw1) = kr1;
        *(short8*)(Vts + sw0) = vr0;
        *(short8*)(Vts + sw1) = vr1;
        __syncthreads();                         // staging visible (+Q/bias on t=0)

        // S^T = K Q^T  (A = K-frag, B = Q-frag)
        floatx4 s_acc[4];
        #pragma unroll
        for (int nt = 0; nt < 4; ++nt) s_acc[nt] = (floatx4){0.f, 0.f, 0.f, 0.f};
        #pragma unroll
        for (int kt = 0; kt < 2; ++kt)
            #pragma unroll
            for (int nt = 0; nt < 4; ++nt) {
                short8 kf = *(const short8*)(Ks + rdoff[kt][nt]);
                s_acc[nt] = __builtin_amdgcn_mfma_f32_16x16x32_bf16(
                    kf, qf[kt], s_acc[nt], 0, 0, 0);
            }

        // prefetch next tile K/V into registers (hides under epilogue/PV)
        if (t + 1 < TILES) {
            gK += 64 * TD; gV += 64;
            kr0 = *(const short8*)gK;
            kr1 = *(const short8*)(gK + (size_t)32 * TD);
            vr0 = *(const short8*)gV;
            vr1 = *(const short8*)(gV + (size_t)32 * NT);
        }

        // epilogue: lane owns keys nt*16+quad*4..+3 for its single q-row
        int base = t * 64 + quad * 4;            // split-local key index
        int hj0 = base / 48;
        int wjb = base - hj0 * 48;
        #pragma unroll
        for (int nt = 0; nt < 4; ++nt) {
            int wj = wjb + nt * 16;
            int hj = hj0 + (wj >= 48 ? 1 : 0);   // local hj in [0,12)
            wj -= (wj >= 48 ? 48 : 0);
            float bh = h2f(BhS[hj * 64 + qrow]);
            short4_t bw4 = *(const short4_t*)(BwS + qrow * 48 + wj);
            float pe[4];
            #pragma unroll
            for (int r = 0; r < 4; ++r) {
                float b = bh + h2f((unsigned short)bw4[r]);
                pe[r] = exp2f(fmaf(0.18033688f, s_acc[nt][r], b));
                lp += pe[r];
            }
            union { unsigned u[2]; short4_t s; } pk;
            pk.u[0] = pkbf(pe[0], pe[1]);
            pk.u[1] = pkbf(pe[2], pe[3]);
            *(short4_t*)(Ps + pwoff[nt]) = pk.s;
        }

        // O += P V : pf from wave-private Ps rows, vf from Vts
        #pragma unroll
        for (int kt = 0; kt < 2; ++kt) {
            short8 pf = *(const short8*)(Ps + poff[kt]);
            #pragma unroll
            for (int nt = 0; nt < 4; ++nt) {
                short8 vf = *(const short8*)(Vts + rdoff[kt][nt]);
                o_acc[nt] = __builtin_amdgcn_mfma_f32_16x16x32_bf16(
                    pf, vf, o_acc[nt], 0, 0, 0);
            }
        }
        __syncthreads();                         // K/V consumed: next stage safe
    }

    // row sums: lane holds partial for its q-row over its quad's keys
    lp += __shfl_xor(lp, 16);
    lp += __shfl_xor(lp, 32);
    if (quad == 0)
        Lpart[((size_t)z * NHEAD + h) * NT + i0 + qrow] = lp;

    unsigned short* op = Opart + (size_t)z * NT * DIM;
    #pragma unroll
    for (int nt = 0; nt < 4; ++nt)
        #pragma unroll
        for (int r = 0; r < 4; ++r)
            op[(size_t)(i0 + wave * 16 + quad * 4 + r) * DIM + h * HD + nt * 16 + lm]
                = f2bf(o_acc[nt][r]);
}

// ---------------------------------------------------------------------------
// Combine splits
// ---------------------------------------------------------------------------
__global__ __launch_bounds__(256)
void k_comb(const unsigned short* __restrict__ Opart, const float* __restrict__ Lpart,
            unsigned short* __restrict__ aob) {
    int gid = blockIdx.x * 256 + threadIdx.x;
    int t = gid / 96, c8 = (gid - t * 96) * 8;
    int h = c8 >> 6;
    float l = 0.f;
    #pragma unroll
    for (int s = 0; s < NSPLIT; ++s)
        l += Lpart[((size_t)s * NHEAD + h) * NT + t];
    float inv = 1.f / l;
    float acc[8] = {0, 0, 0, 0, 0, 0, 0, 0};
    #pragma unroll
    for (int s = 0; s < NSPLIT; ++s) {
        short8 v = *(const short8*)(Opart + (size_t)s * NT * DIM + (size_t)t * DIM + c8);
        #pragma unroll
        for (int i = 0; i < 8; ++i) acc[i] += bf2f((unsigned short)v[i]);
    }
    union { unsigned u[4]; short8 s; } o;
    #pragma unroll
    for (int i = 0; i < 4; ++i) o.u[i] = pkbf(acc[2 * i] * inv, acc[2 * i + 1] * inv);
    *(short8*)(aob + (size_t)t * DIM + c8) = o.s;
}

// ---------------------------------------------------------------------------
extern "C" void kernel_launch(void* const* d_in, const int* in_sizes, int n_in,
                              void* d_out, int out_size, void* d_ws, size_t ws_size,
                              hipStream_t stream) {
    const float* x    = (const float*)d_in[0];
    const float* Wqkv = (const float*)d_in[1];
    const float* bqkv = (const float*)d_in[2];
    const float* Fu   = (const float*)d_in[3];
    const float* Fv   = (const float*)d_in[4];
    const float* qF   = (const float*)d_in[5];
    const float* vF   = (const float*)d_in[6];
    const float* rph  = (const float*)d_in[7];
    const float* rpw  = (const float*)d_in[8];
    const float* Wp   = (const float*)d_in[9];
    const float* bp   = (const float*)d_in[10];

    unsigned short* ws   = (unsigned short*)d_ws;
    unsigned short* qkvb = ws;                               // [2304][2304]
    unsigned short* aob  = qkvb;                             // alias: qkvb dead post-attn
    unsigned short* WpT  = qkvb + (size_t)NT * TD;           // [768][768]
    unsigned short* VtG  = WpT  + (size_t)DIM * DIM;         // [768][2304]
    unsigned short* BhG  = VtG  + (size_t)DIM * NT;          // [12][48][2304] half
    unsigned short* BwT  = BhG  + (size_t)NHEAD * 48 * NT;   // [12][2304][48] half
    float*          Lpart = (float*)(BwT + (size_t)NHEAD * NT * 48); // [4][12][2304]
    unsigned short* tail = (unsigned short*)(Lpart + (size_t)NSPLIT * NHEAD * NT);
    unsigned short* Ax   = tail;                             // [2304][832] (early)
    unsigned short* BqT  = Ax + (size_t)NT * KA;             // [2304][832] (early)
    unsigned short* Opart = tail;                            // [4][2304][768] (late)

    hipLaunchKernelGGL(k_prep, dim3(NT + 576 + 9), dim3(256), 0, stream,
                       x, Fu, qF, vF, Wqkv, Wp, Fv, Ax, BqT, WpT);
    hipLaunchKernelGGL((k_gemm64<128, 0, 1>), dim3(TD / 128, NT / 64), dim3(256), 0,
                       stream, Ax, BqT, bqkv, (void*)qkvb, TD, KA, VtG);
    hipLaunchKernelGGL(k_bias, dim3(48, NHEAD, 2), dim3(256), 0, stream,
                       qkvb, rph, rpw, BhG, BwT);
    hipLaunchKernelGGL(k_attn, dim3(NT / 64, NHEAD, NSPLIT), dim3(256), 0, stream,
                       qkvb, VtG, BhG, BwT, Opart, Lpart);
    hipLaunchKernelGGL(k_comb, dim3(NT * 96 / 256), dim3(256), 0, stream,
                       Opart, Lpart, aob);
    hipLaunchKernelGGL((k_gemm64<64, 1, 0>), dim3(DIM / 64, NT / 64), dim3(256), 0,
                       stream, aob, WpT, bp, d_out, DIM, DIM, (unsigned short*)nullptr);
}